// Round 11
// baseline (372.083 us; speedup 1.0000x reference)
//
#include <hip/hip_runtime.h>

#define DD 48
#define TT 512
#define BB 512
#define STRIDE 64  // padded LDS row stride for bp
#define PF 8       // emit ring depth == inner unroll (static slots)

__device__ __forceinline__ float bperm_f(int addr, float v) {
  return __int_as_float(__builtin_amdgcn_ds_bpermute(addr, __float_as_int(v)));
}
__device__ __forceinline__ float readlane_f(float v, int lane) {
  return __int_as_float(__builtin_amdgcn_readlane(__float_as_int(v), lane));
}
__device__ __forceinline__ float max3f(float a, float b, float c) {
  return fmaxf(fmaxf(a, b), c);
}
__device__ __forceinline__ unsigned umin2(unsigned a, unsigned b) { return a < b ? a : b; }
__device__ __forceinline__ unsigned umin3(unsigned a, unsigned b, unsigned c) {
  return umin2(umin2(a, b), c);
}

// best = max_i s[i]; idx = smallest argmax index (reference tie-break).
// Entirely VCC/SGPR-free: max3 value tree + arithmetic mask + min3_u32 tree.
// Exactness: best is a bitwise copy of some s_k (fmax selection); s_i - best
// == +0.0 iff s_i == best; negative (sign bit set) otherwise, FTZ keeps sign.
__device__ __forceinline__ void argmax48(const float* s, float& best, unsigned& idx) {
  float m1[16];
#pragma unroll
  for (int k = 0; k < 16; ++k) m1[k] = max3f(s[3 * k], s[3 * k + 1], s[3 * k + 2]);
  float m2[6];
#pragma unroll
  for (int k = 0; k < 5; ++k) m2[k] = max3f(m1[3 * k], m1[3 * k + 1], m1[3 * k + 2]);
  m2[5] = m1[15];
  best = fmaxf(max3f(m2[0], m2[1], m2[2]), max3f(m2[3], m2[4], m2[5]));

  unsigned u[DD];
#pragma unroll
  for (int i = 0; i < DD; ++i) {
    int d = __float_as_int(s[i] - best) >> 31;   // 0 iff s[i]==best, else -1
    u[i] = (unsigned)i | (unsigned)d;
  }
  unsigned n1[16];
#pragma unroll
  for (int k = 0; k < 16; ++k) n1[k] = umin3(u[3 * k], u[3 * k + 1], u[3 * k + 2]);
  unsigned n2[6];
#pragma unroll
  for (int k = 0; k < 5; ++k) n2[k] = umin3(n1[3 * k], n1[3 * k + 1], n1[3 * k + 2]);
  n2[5] = n1[15];
  idx = umin2(umin3(n2[0], n2[1], n2[2]), umin3(n2[3], n2[4], n2[5]));
}

__global__ __launch_bounds__(64, 1) void crf_viterbi(const float* __restrict__ logits,
                                                     const int* __restrict__ lens,
                                                     const float* __restrict__ trans,
                                                     int* __restrict__ out) {
  const int b = blockIdx.x;
  const int j = threadIdx.x;          // lanes 0..47 are live tags
  const int jj = j < DD ? j : DD - 1; // clamp for safe reads

  __shared__ unsigned char bp[TT * STRIDE]; // 32 KB backpointers

  float tcol[DD];
#pragma unroll
  for (int i = 0; i < DD; ++i) tcol[i] = trans[i * DD + jj];

  const float* lg = logits + (size_t)b * TT * DD;
  const int L = lens[b];

  float alpha = lg[jj]; // alpha0

  // 8-deep emit ring, static slots (rows 1..8 always allocated: TT=512)
  float e0 = lg[1 * DD + jj], e1 = lg[2 * DD + jj],
        e2 = lg[3 * DD + jj], e3 = lg[4 * DD + jj],
        e4 = lg[5 * DD + jj], e5 = lg[6 * DD + jj],
        e6 = lg[7 * DD + jj], e7 = lg[8 * DD + jj];

  // one step: bpermute broadcast (no SGPR writes), max3 value tree,
  // cmp-free index extraction in the shadow of the next bpermutes.
#define STEP(EV)                                                        \
  {                                                                     \
    float s[DD];                                                        \
    _Pragma("unroll")                                                   \
    for (int i = 0; i < DD; ++i) s[i] = bperm_f(4 * i, alpha) + tcol[i]; \
    float best; unsigned idx;                                           \
    argmax48(s, best, idx);                                             \
    alpha = best + (EV);                                                \
    bp[t * STRIDE + j] = (unsigned char)idx;                            \
  }

#define RELOAD(ES)                                 \
  {                                                \
    int r = t + PF; r = r > TT - 1 ? TT - 1 : r;   \
    ES = lg[r * DD + jj];                          \
  }

  int t = 1;
  while (t < L) {
    STEP(e0); RELOAD(e0); ++t; if (t >= L) break;
    STEP(e1); RELOAD(e1); ++t; if (t >= L) break;
    STEP(e2); RELOAD(e2); ++t; if (t >= L) break;
    STEP(e3); RELOAD(e3); ++t; if (t >= L) break;
    STEP(e4); RELOAD(e4); ++t; if (t >= L) break;
    STEP(e5); RELOAD(e5); ++t; if (t >= L) break;
    STEP(e6); RELOAD(e6); ++t; if (t >= L) break;
    STEP(e7); RELOAD(e7); ++t;
  }
#undef STEP
#undef RELOAD

  __syncthreads(); // single wave; ordering formality before backtrack

  // last_tag = argmax_j alpha (uniform on all lanes; one-time, readlane ok)
  float af[DD];
#pragma unroll
  for (int i = 0; i < DD; ++i) af[i] = readlane_f(alpha, i);
  float bv; unsigned btag;
  argmax48(af, bv, btag);

  int* ob = out + (size_t)b * TT;
  if (j == 0) ob[L - 1] = (int)btag;

  // Backtrack by function composition: H[j] = tag at time t given final tag j.
  int H = j;
  for (int tt = L - 1; tt >= 1; --tt) {
    int v = bp[tt * STRIDE + jj]; // addr independent of H -> pipelined
    H = __shfl(v, H, 64);         // H' = bp_t[H]
    if (j == (int)btag) ob[tt - 1] = H;
  }

  // zero the padded tail t >= L
  for (int tt = L + j; tt < TT; tt += 64) ob[tt] = 0;
}

extern "C" void kernel_launch(void* const* d_in, const int* in_sizes, int n_in,
                              void* d_out, int out_size, void* d_ws, size_t ws_size,
                              hipStream_t stream) {
  const float* logits = (const float*)d_in[0];
  const int* lens     = (const int*)d_in[1];
  const float* trans  = (const float*)d_in[2];
  int* out            = (int*)d_out;
  (void)in_sizes; (void)n_in; (void)out_size; (void)d_ws; (void)ws_size;
  crf_viterbi<<<BB, 64, 0, stream>>>(logits, lens, trans, out);
}